// Round 18
// baseline (693.602 us; speedup 1.0000x reference)
//
#include <hip/hip_runtime.h>
#include <hip/hip_bf16.h>
#include <stdint.h>

// Problem constants (from reference)
#define N_TOK 4096
#define DDIM  2048
#define VOCAB 50257
#define IGNORE_INDEX (-100)

// Tiling
#define BM 128
#define BN 128
#define BK 64                             // fp8 elements per K-tile (64 B/row)
#define NT (DDIM / BK)                    // 32 K-tiles
#define VCHUNKS ((VOCAB + BN - 1) / BN)   // 393
#define VP (VCHUNKS * BN)                 // 50304 padded vocab
#define ROW_TILES (N_TOK / BM)            // 32
#define GRID_MAIN (VCHUNKS * ROW_TILES)   // 12576

#define W_SCALE 32.0f                     // weight pre-scale (power of 2, exact)
#define W_INV   0.03125f
#define SCALE_1 0x7F7F7F7FU               // E8M0 127 = 2^0 in all 4 bytes

typedef float f32x4  __attribute__((ext_vector_type(4)));
typedef float f32x16 __attribute__((ext_vector_type(16)));
typedef int   i32x4  __attribute__((ext_vector_type(4)));
typedef int   i32x8  __attribute__((ext_vector_type(8)));

__device__ __forceinline__ uint32_t pack2bf(float a, float b) {
  uint32_t ua = __float_as_uint(a);
  uint32_t ub = __float_as_uint(b);
  uint32_t ra = (ua + 0x7fffu + ((ua >> 16) & 1u)) >> 16;
  uint32_t rb = (ub + 0x7fffu + ((ub >> 16) & 1u)) & 0xffff0000u;
  return (ra & 0xffffu) | rb;
}

// fp32 -> OCP e4m3 (RNE, saturate-to-448). Manual to guarantee RNE.
__device__ __forceinline__ uint32_t f32_to_e4m3(float f) {
  uint32_t u = __float_as_uint(f);
  uint32_t s = (u >> 24) & 0x80u;
  float a = fabsf(f);
  if (a >= 448.f) return s | 0x7Eu;           // saturate (max finite)
  if (a >= 0.015625f) {                        // normal range 2^-6 .. 448
    uint32_t m = __float_as_uint(a);
    m += 0x7FFFFu + ((m >> 20) & 1u);          // RNE at mantissa bit 20
    uint32_t e = (m >> 23) - 120u;             // exp-127+7 (carry handled)
    return s | (e << 3) | ((m >> 20) & 7u);
  }
  uint32_t m = (uint32_t)rintf(a * 512.f);     // subnormal: multiples of 2^-9
  return s | m;                                // m==8 encodes 2^-6 exactly
}

// ===========================================================================
// Packed MFMA-operand layouts (both operands; r14-verified for B):
// For a 32-row block rb (rows of the operand matrix), K-tile T, piece p in
// {0,1}: 1KB chunk at ((rb*NT + T)*2 + p)*1024, where lane l = hi*32 + r5
// holds row rb*32+r5, k-bytes T*64 + hi*32 + p*16 .. +16.
// Wave loads = coalesced 1KB global_load_dwordx4 per (row-block, p).
// ===========================================================================

// ---------------------------------------------------------------------------
// Prep 1: x fp32[N][D] -> xp e4m3 packed (16 elems/thread)
// ---------------------------------------------------------------------------
__global__ __launch_bounds__(256) void convert_x8(const float* __restrict__ x,
                                                  uint8_t* __restrict__ xp) {
  int t = blockIdx.x * 256 + threadIdx.x;      // N*D/16 threads
  const int n = t >> 7;                        // row (D/16 = 128 pieces/row)
  const int q = t & 127;                       // 16B piece within row
  const float4* src = (const float4*)(x + (size_t)n * DDIM + q * 16);
  uint32_t u[4];
  #pragma unroll
  for (int g = 0; g < 4; ++g) {
    float4 f = src[g];
    u[g] = f32_to_e4m3(f.x) | (f32_to_e4m3(f.y) << 8) |
           (f32_to_e4m3(f.z) << 16) | (f32_to_e4m3(f.w) << 24);
  }
  const int T = q >> 2, rem = q & 3;
  const int hi = rem >> 1, p = rem & 1;
  const int tb = n >> 5, r5 = n & 31;
  const int l = hi * 32 + r5;
  uint8_t* dst = xp + (((size_t)tb * NT + T) * 2 + p) * 1024 + l * 16;
  *(uint4*)dst = make_uint4(u[0], u[1], u[2], u[3]);
}

// ---------------------------------------------------------------------------
// Prep 2 (r18): w fp32[D][V] -> w8p e4m3 PACKED operand order, scaled by 32
// (zero-pad v >= VOCAB). Tile = 64 k x 128 v per block (T = blockIdx.y).
// Phase 1: float4 loads into LDS [64][68] (r17-verified pattern).
// Phase 2: thread (vl = tid>>1, hi = tid&1) emits rows' 32 k-bytes as two
// 16B pieces at chunk((vb32, T), p) + l*16 (l = hi*32 + (vl&31)) -> each
// wave's stores cover whole 1KB chunks (perfectly coalesced).
// ---------------------------------------------------------------------------
__global__ __launch_bounds__(256) void transpose_w8p(const float* __restrict__ w,
                                                     uint8_t* __restrict__ w8p) {
  __shared__ float t[64][68];
  const int vb = blockIdx.x * 128;  // VP/128 = 393 blocks
  const int T  = blockIdx.y;        // D/64 = 32 K-tiles
  const int kb = T * 64;
  const int tid = threadIdx.x;

  const int fq = tid & 31;          // float4 column within tile (v = fq*4)
  const int r8 = tid >> 5;          // row 0..7 per pass
  if (vb + 128 <= VOCAB) {
    #pragma unroll
    for (int i = 0; i < 8; ++i) {
      int kl = r8 + i * 8;
      float4 f = *(const float4*)(w + (size_t)(kb + kl) * VOCAB + vb + fq * 4);
      *(float4*)&t[kl][fq * 4] = make_float4(f.x * W_SCALE, f.y * W_SCALE,
                                             f.z * W_SCALE, f.w * W_SCALE);
    }
  } else {
    #pragma unroll
    for (int i = 0; i < 8; ++i) {
      int kl = r8 + i * 8;
      #pragma unroll
      for (int c = 0; c < 4; ++c) {
        int v = vb + fq * 4 + c;
        t[kl][fq * 4 + c] =
            (v < VOCAB) ? w[(size_t)(kb + kl) * VOCAB + v] * W_SCALE : 0.f;
      }
    }
  }
  __syncthreads();

  const int vl = tid >> 1, hi = tid & 1;
  const int vb32 = (vb >> 5) + (vl >> 5);
  const int r5 = vl & 31;
  const int l = hi * 32 + r5;
  uint32_t u[8];
  #pragma unroll
  for (int g = 0; g < 8; ++g) {
    u[g] = 0;
    #pragma unroll
    for (int j = 0; j < 4; ++j)
      u[g] |= f32_to_e4m3(t[hi * 32 + g * 4 + j][vl]) << (8 * j);
  }
  uint8_t* base = w8p + (((size_t)vb32 * NT + T) * 2) * 1024 + l * 16;
  *(uint4*)base = make_uint4(u[0], u[1], u[2], u[3]);            // p = 0
  *(uint4*)(base + 1024) = make_uint4(u[4], u[5], u[6], u[7]);   // p = 1
}

// ---------------------------------------------------------------------------
// Main (r18): MX-scaled FP8 GEMM, BOTH operands from packed global into
// registers -> NO LDS, NO barriers in the K-loop. Per wave per tile:
// 8 coalesced 1KB loads (A: row-blocks wn*2+bi; B: wm*2+bj) + 4 MX MFMA.
// 12 free-running waves/CU hide L2/L3 latency; LDS pipe eliminated.
// C/D 32x32 layout (r8-verified): col(token) = lane&31,
// row(vocab) = (reg&3) + 8*(reg>>2) + 4*(lane>>5).
// launch_bounds(256,3): acc 64 AGPR + 2x(A16+B16) + addr ~ 148 < 170.
// ---------------------------------------------------------------------------
struct Oregs { i32x4 v[2][2]; };             // [row-block][p] 16B pieces

__global__ __launch_bounds__(256, 3) void lmhead_main(
    const uint8_t* __restrict__ w8p, const uint8_t* __restrict__ xp,
    const int* __restrict__ tgt,
    float2* __restrict__ partial, float* __restrict__ tlogit)
{
  __shared__ float2 stats[2][BM];

  const int bid = blockIdx.x;
  const int v = bid >> 5;              // chunk-major: 32 row-tiles share panel
  const int r = bid & 31;
  const int v0 = v * BN;
  const int m0 = r * BM;
  const int tid = threadIdx.x;
  const int lane = tid & 63;
  const int wid = tid >> 6;
  const int wn = wid >> 1, wm = wid & 1;   // wn: vocab half, wm: token half
  const int r5 = lane & 31, hi = lane >> 5;

  f32x16 acc[2][2];
  #pragma unroll
  for (int i = 0; i < 2; ++i)
    #pragma unroll
    for (int j = 0; j < 2; ++j) acc[i][j] = (f32x16)0.f;

  // ---- packed-global bases (per-lane constants) ----
  const int ab0 = (v0 >> 5) + wn * 2;     // A row-block for bi=0
  const uint8_t* wa0 = w8p + ((size_t)ab0 * NT) * 2048 + lane * 16;
  const uint8_t* wa1 = w8p + ((size_t)(ab0 + 1) * NT) * 2048 + lane * 16;
  const int tb0 = (m0 >> 5) + wm * 2;     // B row-block for bj=0
  const uint8_t* xb0 = xp + ((size_t)tb0 * NT) * 2048 + lane * 16;
  const uint8_t* xb1 = xp + ((size_t)(tb0 + 1) * NT) * 2048 + lane * 16;

  auto loadA = [&](Oregs& A, int T) {
    const uint8_t* p0 = wa0 + (size_t)T * 2048;
    const uint8_t* p1 = wa1 + (size_t)T * 2048;
    A.v[0][0] = *(const i32x4*)(p0);
    A.v[0][1] = *(const i32x4*)(p0 + 1024);
    A.v[1][0] = *(const i32x4*)(p1);
    A.v[1][1] = *(const i32x4*)(p1 + 1024);
  };
  auto loadB = [&](Oregs& B, int T) {
    const uint8_t* p0 = xb0 + (size_t)T * 2048;
    const uint8_t* p1 = xb1 + (size_t)T * 2048;
    B.v[0][0] = *(const i32x4*)(p0);
    B.v[0][1] = *(const i32x4*)(p0 + 1024);
    B.v[1][0] = *(const i32x4*)(p1);
    B.v[1][1] = *(const i32x4*)(p1 + 1024);
  };
  auto computeT = [&](const Oregs& A, const Oregs& B) {
    i32x8 av[2], bv[2];
    #pragma unroll
    for (int k = 0; k < 2; ++k) {
      av[k] = __builtin_shufflevector(A.v[k][0], A.v[k][1], 0, 1, 2, 3, 4, 5, 6, 7);
      bv[k] = __builtin_shufflevector(B.v[k][0], B.v[k][1], 0, 1, 2, 3, 4, 5, 6, 7);
    }
    #pragma unroll
    for (int bi = 0; bi < 2; ++bi)
      #pragma unroll
      for (int bj = 0; bj < 2; ++bj)
        acc[bi][bj] = __builtin_amdgcn_mfma_scale_f32_32x32x64_f8f6f4(
            av[bi], bv[bj], acc[bi][bj], 0 /*A fmt fp8*/, 0 /*B fmt fp8*/,
            0, SCALE_1, 0, SCALE_1);
  };

  Oregs A0, A1, B0, B1;
  loadA(A0, 0); loadB(B0, 0);
  for (int t = 0; t < NT; t += 2) {        // no barriers: waves free-run
    if (t + 1 < NT) { loadA(A1, t + 1); loadB(B1, t + 1); }
    computeT(A0, B0);
    if (t + 2 < NT) { loadA(A0, t + 2); loadB(B0, t + 2); }
    computeT(A1, B1);
  }

  // ---- epilogue: per-token max & sum-exp over this wave's 64 vocab rows ----
  #pragma unroll
  for (int bj = 0; bj < 2; ++bj) {
    const int m_g = m0 + wm * 64 + bj * 32 + r5;
    float vmax = -INFINITY;
    #pragma unroll
    for (int bi = 0; bi < 2; ++bi) {
      #pragma unroll
      for (int rg = 0; rg < 16; ++rg) {
        int n_g = v0 + wn * 64 + bi * 32 + (rg & 3) + 8 * (rg >> 2) + 4 * hi;
        if (n_g < VOCAB) vmax = fmaxf(vmax, acc[bi][bj][rg] * W_INV);
      }
    }
    vmax = fmaxf(vmax, __shfl_xor(vmax, 32, 64));
    float ssum = 0.f;
    const int t = tgt[m_g];
    #pragma unroll
    for (int bi = 0; bi < 2; ++bi) {
      #pragma unroll
      for (int rg = 0; rg < 16; ++rg) {
        int n_g = v0 + wn * 64 + bi * 32 + (rg & 3) + 8 * (rg >> 2) + 4 * hi;
        float val = acc[bi][bj][rg] * W_INV;
        if (n_g < VOCAB) ssum += __expf(val - vmax);
        if (n_g == t) tlogit[m_g] = val;
      }
    }
    ssum += __shfl_xor(ssum, 32, 64);
    if (hi == 0) stats[wn][wm * 64 + bj * 32 + r5] = make_float2(vmax, ssum);
  }
  __syncthreads();
  if (tid < BM) {
    float2 a = stats[0][tid], b = stats[1][tid];
    float M = fmaxf(a.x, b.x);
    float S = a.y * __expf(a.x - M) + b.y * __expf(b.x - M);
    partial[(size_t)(m0 + tid) * VCHUNKS + v] = make_float2(M, S);
  }
}

// ---------------------------------------------------------------------------
// Fallback (round-1 kernel, bf16 path from fp32 inputs): if ws too small.
// ---------------------------------------------------------------------------
typedef short bf16x8 __attribute__((ext_vector_type(8)));

__global__ __launch_bounds__(256, 2) void lmhead_partial_fb(
    const float* __restrict__ x, const float* __restrict__ w,
    const int* __restrict__ tgt,
    float2* __restrict__ partial, float* __restrict__ tlogit)
{
  __shared__ uint4 xs[BM * 64 * 2 / 16];
  __shared__ uint4 wtl[BN * 64 * 2 / 16];
  __shared__ float2 stats[2][BM];

  const int bid = blockIdx.x;
  const int v = bid >> 5;
  const int r = bid & 31;
  const int v0 = v * BN;
  const int m0 = r * BM;
  const int tid = threadIdx.x;
  const int lane = tid & 63;
  const int wid = tid >> 6;
  const int wn = wid >> 1, wm = wid & 1;
  const int lr = lane & 15, lk = lane >> 4;

  f32x4 acc[4][4];
  #pragma unroll
  for (int i = 0; i < 4; ++i)
    #pragma unroll
    for (int j = 0; j < 4; ++j) acc[i][j] = (f32x4)0.f;

  char* xsb = (char*)xs;
  char* wtb = (char*)wtl;

  for (int kt = 0; kt < DDIM / 64; ++kt) {
    const int k0 = kt * 64;
    __syncthreads();
    #pragma unroll
    for (int i = 0; i < 4; ++i) {
      int t = tid + i * 256;
      int m = t >> 3, kg = t & 7;
      const float* gp = x + (size_t)(m0 + m) * DDIM + k0 + kg * 8;
      float4 f0 = *(const float4*)gp;
      float4 f1 = *(const float4*)(gp + 4);
      uint4 pk;
      pk.x = pack2bf(f0.x, f0.y); pk.y = pack2bf(f0.z, f0.w);
      pk.z = pack2bf(f1.x, f1.y); pk.w = pack2bf(f1.z, f1.w);
      int byte = (m * 128 + kg * 16) ^ ((m & 7) << 4);
      *(uint4*)(xsb + byte) = pk;
    }
    #pragma unroll
    for (int i = 0; i < 4; ++i) {
      int t = tid + i * 256;
      int n = t & 127, kg = t >> 7;
      int col = v0 + n;
      float f[8];
      if (col < VOCAB) {
        const float* gp = w + (size_t)(k0 + kg * 8) * VOCAB + col;
        #pragma unroll
        for (int kk = 0; kk < 8; ++kk) f[kk] = gp[(size_t)kk * VOCAB];
      } else {
        #pragma unroll
        for (int kk = 0; kk < 8; ++kk) f[kk] = 0.f;
      }
      uint4 pk;
      pk.x = pack2bf(f[0], f[1]); pk.y = pack2bf(f[2], f[3]);
      pk.z = pack2bf(f[4], f[5]); pk.w = pack2bf(f[6], f[7]);
      int byte = (n * 128 + kg * 16) ^ ((n & 7) << 4);
      *(uint4*)(wtb + byte) = pk;
    }
    __syncthreads();
    #pragma unroll
    for (int ks = 0; ks < 2; ++ks) {
      bf16x8 af[4], bfr[4];
      #pragma unroll
      for (int bi = 0; bi < 4; ++bi) {
        int row = wn * 64 + bi * 16 + lr;
        int byte = (row * 128 + ks * 64 + lk * 16) ^ ((row & 7) << 4);
        af[bi] = *(const bf16x8*)(wtb + byte);
      }
      #pragma unroll
      for (int bj = 0; bj < 4; ++bj) {
        int row = wm * 64 + bj * 16 + lr;
        int byte = (row * 128 + ks * 64 + lk * 16) ^ ((row & 7) << 4);
        bfr[bj] = *(const bf16x8*)(xsb + byte);
      }
      #pragma unroll
      for (int bi = 0; bi < 4; ++bi)
        #pragma unroll
        for (int bj = 0; bj < 4; ++bj)
          acc[bi][bj] = __builtin_amdgcn_mfma_f32_16x16x32_bf16(
              af[bi], bfr[bj], acc[bi][bj], 0, 0, 0);
    }
  }

  #pragma unroll
  for (int bj = 0; bj < 4; ++bj) {
    const int m_g = m0 + wm * 64 + bj * 16 + lr;
    float vmax = -INFINITY;
    #pragma unroll
    for (int bi = 0; bi < 4; ++bi)
      #pragma unroll
      for (int rg = 0; rg < 4; ++rg) {
        int n_g = v0 + wn * 64 + bi * 16 + lk * 4 + rg;
        if (n_g < VOCAB) vmax = fmaxf(vmax, acc[bi][bj][rg]);
      }
    vmax = fmaxf(vmax, __shfl_xor(vmax, 16, 64));
    vmax = fmaxf(vmax, __shfl_xor(vmax, 32, 64));
    float ssum = 0.f;
    const int t = tgt[m_g];
    #pragma unroll
    for (int bi = 0; bi < 4; ++bi)
      #pragma unroll
      for (int rg = 0; rg < 4; ++rg) {
        int n_g = v0 + wn * 64 + bi * 16 + lk * 4 + rg;
        float val = acc[bi][bj][rg];
        if (n_g < VOCAB) ssum += __expf(val - vmax);
        if (n_g == t) tlogit[m_g] = val;
      }
    ssum += __shfl_xor(ssum, 16, 64);
    ssum += __shfl_xor(ssum, 32, 64);
    if (lk == 0) stats[wn][wm * 64 + bj * 16 + lr] = make_float2(vmax, ssum);
  }
  __syncthreads();
  if (tid < BM) {
    float2 a = stats[0][tid], b = stats[1][tid];
    float M = fmaxf(a.x, b.x);
    float S = a.y * __expf(a.x - M) + b.y * __expf(b.x - M);
    partial[(size_t)(m0 + tid) * VCHUNKS + v] = make_float2(M, S);
  }
}

// ---------------------------------------------------------------------------
// Reduce: per-row merge of chunk partials -> lse; loss sum into d_out[0].
// ---------------------------------------------------------------------------
__device__ __forceinline__ void lse_merge(float& m, float& s, float M, float S) {
  if (S > 0.f) {
    if (M > m) { s = s * __expf(m - M) + S; m = M; }
    else       { s += S * __expf(M - m); }
  }
}

__global__ void lmhead_reduce(const float2* __restrict__ partial,
                              const float* __restrict__ tlogit,
                              const int* __restrict__ tgt,
                              float* __restrict__ out)
{
  const int wid = threadIdx.x >> 6;
  const int lane = threadIdx.x & 63;
  const int row = blockIdx.x * 4 + wid;
  float m = -INFINITY, s = 0.f;
  for (int c = lane; c < VCHUNKS; c += 64) {
    float2 p = partial[(size_t)row * VCHUNKS + c];
    lse_merge(m, s, p.x, p.y);
  }
  #pragma unroll
  for (int off = 1; off < 64; off <<= 1) {
    float M = __shfl_xor(m, off, 64);
    float S = __shfl_xor(s, off, 64);
    lse_merge(m, s, M, S);
  }
  if (lane == 0) {
    int t = tgt[row];
    if (t != IGNORE_INDEX) {
      float loss = m + __logf(s) - tlogit[row];
      atomicAdd(out, loss);
    }
  }
}

extern "C" void kernel_launch(void* const* d_in, const int* in_sizes, int n_in,
                              void* d_out, int out_size, void* d_ws, size_t ws_size,
                              hipStream_t stream) {
  const float* x = (const float*)d_in[0];
  const float* w = (const float*)d_in[1];
  const int* tgt = (const int*)d_in[2];
  float* out = (float*)d_out;

  const size_t w8_bytes = (size_t)VP * DDIM;             // ~103 MB
  const size_t x8_bytes = (size_t)N_TOK * DDIM;          // 8.4 MB
  const size_t part_bytes = (size_t)N_TOK * VCHUNKS * 8; // ~12.9 MB
  const size_t tl_bytes = (size_t)N_TOK * 4;
  const size_t need = w8_bytes + x8_bytes + part_bytes + tl_bytes;

  hipMemsetAsync(d_out, 0, sizeof(float), stream);

  if (ws_size >= need) {
    uint8_t* w8p = (uint8_t*)d_ws;
    uint8_t* xp = (uint8_t*)d_ws + w8_bytes;
    float2* partial = (float2*)((char*)d_ws + w8_bytes + x8_bytes);
    float* tlogit = (float*)((char*)d_ws + w8_bytes + x8_bytes + part_bytes);

    convert_x8<<<dim3(N_TOK * DDIM / 16 / 256), 256, 0, stream>>>(x, xp);
    transpose_w8p<<<dim3(VP / 128, DDIM / 64), 256, 0, stream>>>(w, w8p);
    lmhead_main<<<dim3(GRID_MAIN), 256, 0, stream>>>(w8p, xp, tgt, partial, tlogit);
    lmhead_reduce<<<dim3(N_TOK / 4), 256, 0, stream>>>(partial, tlogit, tgt, out);
  } else {
    float2* partial = (float2*)d_ws;
    float* tlogit = (float*)((char*)d_ws + part_bytes);
    lmhead_partial_fb<<<dim3(GRID_MAIN), 256, 0, stream>>>(x, w, tgt, partial, tlogit);
    lmhead_reduce<<<dim3(N_TOK / 4), 256, 0, stream>>>(partial, tlogit, tgt, out);
  }
}

// Round 19
// 690.380 us; speedup vs baseline: 1.0047x; 1.0047x over previous
//
#include <hip/hip_runtime.h>
#include <hip/hip_bf16.h>
#include <stdint.h>

// Problem constants (from reference)
#define N_TOK 4096
#define DDIM  2048
#define VOCAB 50257
#define IGNORE_INDEX (-100)

// Tiling
#define BM 128
#define BN 128
#define BK 64                             // fp8 elements per K-tile (64 B/row)
#define NT (DDIM / BK)                    // 32 K-tiles
#define VCHUNKS ((VOCAB + BN - 1) / BN)   // 393
#define VP (VCHUNKS * BN)                 // 50304 padded vocab
#define ROW_TILES (N_TOK / BM)            // 32
#define GRID_MAIN (VCHUNKS * ROW_TILES)   // 12576 = 8 * 1572
#define CPX (GRID_MAIN / 8)               // 1572 blocks per XCD

#define W_SCALE 32.0f                     // weight pre-scale (power of 2, exact)
#define W_INV   0.03125f
#define SCALE_1 0x7F7F7F7FU               // E8M0 127 = 2^0 in all 4 bytes

typedef float f32x4  __attribute__((ext_vector_type(4)));
typedef float f32x16 __attribute__((ext_vector_type(16)));
typedef int   i32x4  __attribute__((ext_vector_type(4)));
typedef int   i32x8  __attribute__((ext_vector_type(8)));

__device__ __forceinline__ uint32_t pack2bf(float a, float b) {
  uint32_t ua = __float_as_uint(a);
  uint32_t ub = __float_as_uint(b);
  uint32_t ra = (ua + 0x7fffu + ((ua >> 16) & 1u)) >> 16;
  uint32_t rb = (ub + 0x7fffu + ((ub >> 16) & 1u)) & 0xffff0000u;
  return (ra & 0xffffu) | rb;
}

// fp32 -> OCP e4m3 (RNE, saturate-to-448). Manual to guarantee RNE.
__device__ __forceinline__ uint32_t f32_to_e4m3(float f) {
  uint32_t u = __float_as_uint(f);
  uint32_t s = (u >> 24) & 0x80u;
  float a = fabsf(f);
  if (a >= 448.f) return s | 0x7Eu;           // saturate (max finite)
  if (a >= 0.015625f) {                        // normal range 2^-6 .. 448
    uint32_t m = __float_as_uint(a);
    m += 0x7FFFFu + ((m >> 20) & 1u);          // RNE at mantissa bit 20
    uint32_t e = (m >> 23) - 120u;             // exp-127+7 (carry handled)
    return s | (e << 3) | ((m >> 20) & 7u);
  }
  uint32_t m = (uint32_t)rintf(a * 512.f);     // subnormal: multiples of 2^-9
  return s | m;                                // m==8 encodes 2^-6 exactly
}

__device__ __forceinline__ void gload_lds16(const void* g, void* l) {
  __builtin_amdgcn_global_load_lds(
      (const __attribute__((address_space(1))) uint32_t*)g,
      (__attribute__((address_space(3))) uint32_t*)l, 16, 0, 0);
}

// ===========================================================================
// xp packed layout (B operand in MFMA order): for token-block tb (32 rows),
// K-tile T, piece p in {0,1}: 1KB chunk at ((tb*NT + T)*2 + p)*1024, where
// lane l = hi*32 + r5 holds row (tb*32+r5), k-bytes T*64 + hi*32 + p*16.
// loadB = coalesced 1KB global_load_dwordx4 per (bj, p).
// ===========================================================================

// ---------------------------------------------------------------------------
// Prep 1: x fp32[N][D] -> xp e4m3 packed (16 elems/thread)
// ---------------------------------------------------------------------------
__global__ __launch_bounds__(256) void convert_x8(const float* __restrict__ x,
                                                  uint8_t* __restrict__ xp) {
  int t = blockIdx.x * 256 + threadIdx.x;      // N*D/16 threads
  const int n = t >> 7;                        // row (D/16 = 128 pieces/row)
  const int q = t & 127;                       // 16B piece within row
  const float4* src = (const float4*)(x + (size_t)n * DDIM + q * 16);
  uint32_t u[4];
  #pragma unroll
  for (int g = 0; g < 4; ++g) {
    float4 f = src[g];
    u[g] = f32_to_e4m3(f.x) | (f32_to_e4m3(f.y) << 8) |
           (f32_to_e4m3(f.z) << 16) | (f32_to_e4m3(f.w) << 24);
  }
  const int T = q >> 2, rem = q & 3;
  const int hi = rem >> 1, p = rem & 1;
  const int tb = n >> 5, r5 = n & 31;
  const int l = hi * 32 + r5;
  uint8_t* dst = xp + (((size_t)tb * NT + T) * 2 + p) * 1024 + l * 16;
  *(uint4*)dst = make_uint4(u[0], u[1], u[2], u[3]);
}

// ---------------------------------------------------------------------------
// Prep 2 (r17-verified): w fp32[D][V] -> w8 e4m3[VP][D] linear k, x32.
// Tile = 64 k x 128 v; float4 loads -> LDS [64][68]; 32B/thread stores.
// ---------------------------------------------------------------------------
__global__ __launch_bounds__(256) void transpose_w8(const float* __restrict__ w,
                                                    uint8_t* __restrict__ w8) {
  __shared__ float t[64][68];
  const int vb = blockIdx.x * 128;  // VP/128 = 393 blocks
  const int kb = blockIdx.y * 64;   // D/64  = 32 blocks
  const int tid = threadIdx.x;

  const int fq = tid & 31;          // float4 column within tile (v = fq*4)
  const int r8 = tid >> 5;          // row 0..7 per pass
  if (vb + 128 <= VOCAB) {
    #pragma unroll
    for (int i = 0; i < 8; ++i) {
      int kl = r8 + i * 8;
      float4 f = *(const float4*)(w + (size_t)(kb + kl) * VOCAB + vb + fq * 4);
      *(float4*)&t[kl][fq * 4] = make_float4(f.x * W_SCALE, f.y * W_SCALE,
                                             f.z * W_SCALE, f.w * W_SCALE);
    }
  } else {
    #pragma unroll
    for (int i = 0; i < 8; ++i) {
      int kl = r8 + i * 8;
      #pragma unroll
      for (int c = 0; c < 4; ++c) {
        int v = vb + fq * 4 + c;
        t[kl][fq * 4 + c] =
            (v < VOCAB) ? w[(size_t)(kb + kl) * VOCAB + v] * W_SCALE : 0.f;
      }
    }
  }
  __syncthreads();

  const int vl = tid >> 1, half = tid & 1;
  uint32_t u[8];
  #pragma unroll
  for (int g = 0; g < 8; ++g) {
    u[g] = 0;
    #pragma unroll
    for (int j = 0; j < 4; ++j)
      u[g] |= f32_to_e4m3(t[half * 32 + g * 4 + j][vl]) << (8 * j);
  }
  uint8_t* dst = w8 + (size_t)(vb + vl) * DDIM + kb + half * 32;
  *(uint4*)dst = make_uint4(u[0], u[1], u[2], u[3]);
  *(uint4*)(dst + 16) = make_uint4(u[4], u[5], u[6], u[7]);
}

// ---------------------------------------------------------------------------
// Main: MX-scaled FP8 GEMM (scales=1.0) fused with online-softmax partials.
// r14 kernel (best: 483 us) + r19 bijective XCD swizzle: consecutive logical
// blocks (sharing a weight panel) run on the SAME XCD -> the 256KB A-panel
// stays hot in that XCD's 4MB L2 across its 32 row-tile blocks (T1; FETCH
// was 4.3x unique bytes without it).
// A via LDS (r10 placement, 2-buffer, distance-1); B from packed global.
// C/D 32x32 layout (r8-verified). launch_bounds(256,3): no spill.
// ---------------------------------------------------------------------------
struct Bregs { i32x4 v[2][2]; };             // [bj][p] 16B pieces

__global__ __launch_bounds__(256, 3) void lmhead_main(
    const uint8_t* __restrict__ w8, const uint8_t* __restrict__ xp,
    const int* __restrict__ tgt,
    float2* __restrict__ partial, float* __restrict__ tlogit)
{
  __shared__ char lds[16384];          // 2 bufs x (A 8K)
  __shared__ float2 stats[2][BM];

  // Bijective XCD swizzle (GRID_MAIN = 8 * CPX exactly): dispatch
  // round-robins XCDs (xcd = bid%8); give each XCD a contiguous logical span.
  const int bid0 = blockIdx.x;
  const int bid = (bid0 & 7) * CPX + (bid0 >> 3);
  const int v = bid >> 5;              // chunk-major: 32 row-tiles share panel
  const int r = bid & 31;
  const int v0 = v * BN;
  const int m0 = r * BM;
  const int tid = threadIdx.x;
  const int lane = tid & 63;
  const int wid = tid >> 6;
  const int wn = wid >> 1, wm = wid & 1;   // wn: vocab half, wm: token half

  f32x16 acc[2][2];
  #pragma unroll
  for (int i = 0; i < 2; ++i)
    #pragma unroll
    for (int j = 0; j < 2; ++j) acc[i][j] = (f32x16)0.f;

  // ---- A staging source mapping (per-lane constants; r10 placement) ----
  const int jj = lane >> 3;
  const int lu_s = (lane & 7) ^ jj;
  const int srow = 2 * jj + (lu_s >> 2);
  const int sk = (lu_s & 3) * 16;
  const uint8_t* wsrc = w8 + (size_t)(v0 + srow) * DDIM + sk;

  // ---- A fragment-read offsets (per-lane constants; r10 placement) ----
  const int r5 = lane & 31, hi = lane >> 5;
  const int j7 = (r5 >> 1) & 7;
  const int lu0 = ((r5 & 1) << 2) | (hi << 1);
  const int rdoff = (r5 >> 1) * 128 + ((lu0 ^ j7) << 4);
  const int aoff0 = wn * 4096 + rdoff;   // + bi*2048 per row-block

  // ---- B packed-global bases (per-lane constants) ----
  const int tb0 = (m0 >> 5) + wm * 2;    // token-32-block index for bj=0
  const uint8_t* xb0 = xp + ((size_t)tb0 * NT) * 2048 + lane * 16;
  const uint8_t* xb1 = xp + ((size_t)(tb0 + 1) * NT) * 2048 + lane * 16;

  // stage A of K-tile T into buf s: per wave 2 chunks (block: 8 x 1KB)
  auto stageA = [&](int T, int s) {
    char* Al = lds + s * 8192;
    const size_t ko = (size_t)T * BK;
    #pragma unroll
    for (int i = 0; i < 2; ++i) {
      int c = wid * 2 + i;                 // chunk 0..7 (16 rows each)
      gload_lds16(wsrc + (size_t)c * 16 * DDIM + ko, Al + c * 1024);
    }
  };
  // load B of K-tile T into register set (static indices only)
  auto loadB = [&](Bregs& B, int T) {
    const uint8_t* p0 = xb0 + (size_t)T * 2048;
    const uint8_t* p1 = xb1 + (size_t)T * 2048;
    B.v[0][0] = *(const i32x4*)(p0);
    B.v[0][1] = *(const i32x4*)(p0 + 1024);
    B.v[1][0] = *(const i32x4*)(p1);
    B.v[1][1] = *(const i32x4*)(p1 + 1024);
  };
  // compute one K-tile: A from LDS buf, B from registers
  auto computeT = [&](const char* Al, const Bregs& B) {
    i32x8 bv[2];
    #pragma unroll
    for (int bj = 0; bj < 2; ++bj)
      bv[bj] = __builtin_shufflevector(B.v[bj][0], B.v[bj][1],
                                       0, 1, 2, 3, 4, 5, 6, 7);
    #pragma unroll
    for (int bi = 0; bi < 2; ++bi) {
      i32x4 a0 = *(const i32x4*)(Al + (aoff0 + bi * 2048));
      i32x4 a1 = *(const i32x4*)(Al + ((aoff0 ^ 16) + bi * 2048));
      i32x8 av = __builtin_shufflevector(a0, a1, 0, 1, 2, 3, 4, 5, 6, 7);
      #pragma unroll
      for (int bj = 0; bj < 2; ++bj)
        acc[bi][bj] = __builtin_amdgcn_mfma_scale_f32_32x32x64_f8f6f4(
            av, bv[bj], acc[bi][bj], 0 /*A fmt fp8*/, 0 /*B fmt fp8*/,
            0, SCALE_1, 0, SCALE_1);
    }
  };

  Bregs B0, B1;
  stageA(0, 0);
  loadB(B0, 0);
  __syncthreads();                         // A buf0 ready

  for (int t = 0; t < NT; t += 2) {        // NT even; manual 2x unroll
    // half 1: compute tile t from buf0/B0; prefetch t+1 into buf1/B1
    if (t + 1 < NT) { stageA(t + 1, 1); loadB(B1, t + 1); }
    computeT(lds, B0);
    __syncthreads();                       // buf0 reads done; t+1 landed
    // half 2: compute tile t+1 from buf1/B1; prefetch t+2 into buf0/B0
    if (t + 2 < NT) { stageA(t + 2, 0); loadB(B0, t + 2); }
    computeT(lds + 8192, B1);
    __syncthreads();                       // buf1 reads done; t+2 landed
  }

  // ---- epilogue: per-token max & sum-exp over this wave's 64 vocab rows ----
  #pragma unroll
  for (int bj = 0; bj < 2; ++bj) {
    const int m_g = m0 + wm * 64 + bj * 32 + r5;
    float vmax = -INFINITY;
    #pragma unroll
    for (int bi = 0; bi < 2; ++bi) {
      #pragma unroll
      for (int rg = 0; rg < 16; ++rg) {
        int n_g = v0 + wn * 64 + bi * 32 + (rg & 3) + 8 * (rg >> 2) + 4 * hi;
        if (n_g < VOCAB) vmax = fmaxf(vmax, acc[bi][bj][rg] * W_INV);
      }
    }
    vmax = fmaxf(vmax, __shfl_xor(vmax, 32, 64));
    float ssum = 0.f;
    const int t = tgt[m_g];
    #pragma unroll
    for (int bi = 0; bi < 2; ++bi) {
      #pragma unroll
      for (int rg = 0; rg < 16; ++rg) {
        int n_g = v0 + wn * 64 + bi * 32 + (rg & 3) + 8 * (rg >> 2) + 4 * hi;
        float val = acc[bi][bj][rg] * W_INV;
        if (n_g < VOCAB) ssum += __expf(val - vmax);
        if (n_g == t) tlogit[m_g] = val;
      }
    }
    ssum += __shfl_xor(ssum, 32, 64);
    if (hi == 0) stats[wn][wm * 64 + bj * 32 + r5] = make_float2(vmax, ssum);
  }
  __syncthreads();
  if (tid < BM) {
    float2 a = stats[0][tid], b = stats[1][tid];
    float M = fmaxf(a.x, b.x);
    float S = a.y * __expf(a.x - M) + b.y * __expf(b.x - M);
    partial[(size_t)(m0 + tid) * VCHUNKS + v] = make_float2(M, S);
  }
}

// ---------------------------------------------------------------------------
// Fallback (round-1 kernel, bf16 path from fp32 inputs): if ws too small.
// ---------------------------------------------------------------------------
typedef short bf16x8 __attribute__((ext_vector_type(8)));

__global__ __launch_bounds__(256, 2) void lmhead_partial_fb(
    const float* __restrict__ x, const float* __restrict__ w,
    const int* __restrict__ tgt,
    float2* __restrict__ partial, float* __restrict__ tlogit)
{
  __shared__ uint4 xs[BM * 64 * 2 / 16];
  __shared__ uint4 wtl[BN * 64 * 2 / 16];
  __shared__ float2 stats[2][BM];

  const int bid = blockIdx.x;
  const int v = bid >> 5;
  const int r = bid & 31;
  const int v0 = v * BN;
  const int m0 = r * BM;
  const int tid = threadIdx.x;
  const int lane = tid & 63;
  const int wid = tid >> 6;
  const int wn = wid >> 1, wm = wid & 1;
  const int lr = lane & 15, lk = lane >> 4;

  f32x4 acc[4][4];
  #pragma unroll
  for (int i = 0; i < 4; ++i)
    #pragma unroll
    for (int j = 0; j < 4; ++j) acc[i][j] = (f32x4)0.f;

  char* xsb = (char*)xs;
  char* wtb = (char*)wtl;

  for (int kt = 0; kt < DDIM / 64; ++kt) {
    const int k0 = kt * 64;
    __syncthreads();
    #pragma unroll
    for (int i = 0; i < 4; ++i) {
      int t = tid + i * 256;
      int m = t >> 3, kg = t & 7;
      const float* gp = x + (size_t)(m0 + m) * DDIM + k0 + kg * 8;
      float4 f0 = *(const float4*)gp;
      float4 f1 = *(const float4*)(gp + 4);
      uint4 pk;
      pk.x = pack2bf(f0.x, f0.y); pk.y = pack2bf(f0.z, f0.w);
      pk.z = pack2bf(f1.x, f1.y); pk.w = pack2bf(f1.z, f1.w);
      int byte = (m * 128 + kg * 16) ^ ((m & 7) << 4);
      *(uint4*)(xsb + byte) = pk;
    }
    #pragma unroll
    for (int i = 0; i < 4; ++i) {
      int t = tid + i * 256;
      int n = t & 127, kg = t >> 7;
      int col = v0 + n;
      float f[8];
      if (col < VOCAB) {
        const float* gp = w + (size_t)(k0 + kg * 8) * VOCAB + col;
        #pragma unroll
        for (int kk = 0; kk < 8; ++kk) f[kk] = gp[(size_t)kk * VOCAB];
      } else {
        #pragma unroll
        for (int kk = 0; kk < 8; ++kk) f[kk] = 0.f;
      }
      uint4 pk;
      pk.x = pack2bf(f[0], f[1]); pk.y = pack2bf(f[2], f[3]);
      pk.z = pack2bf(f[4], f[5]); pk.w = pack2bf(f[6], f[7]);
      int byte = (n * 128 + kg * 16) ^ ((n & 7) << 4);
      *(uint4*)(wtb + byte) = pk;
    }
    __syncthreads();
    #pragma unroll
    for (int ks = 0; ks < 2; ++ks) {
      bf16x8 af[4], bfr[4];
      #pragma unroll
      for (int bi = 0; bi < 4; ++bi) {
        int row = wn * 64 + bi * 16 + lr;
        int byte = (row * 128 + ks * 64 + lk * 16) ^ ((row & 7) << 4);
        af[bi] = *(const bf16x8*)(wtb + byte);
      }
      #pragma unroll
      for (int bj = 0; bj < 4; ++bj) {
        int row = wm * 64 + bj * 16 + lr;
        int byte = (row * 128 + ks * 64 + lk * 16) ^ ((row & 7) << 4);
        bfr[bj] = *(const bf16x8*)(xsb + byte);
      }
      #pragma unroll
      for (int bi = 0; bi < 4; ++bi)
        #pragma unroll
        for (int bj = 0; bj < 4; ++bj)
          acc[bi][bj] = __builtin_amdgcn_mfma_f32_16x16x32_bf16(
              af[bi], bfr[bj], acc[bi][bj], 0, 0, 0);
    }
  }

  #pragma unroll
  for (int bj = 0; bj < 4; ++bj) {
    const int m_g = m0 + wm * 64 + bj * 16 + lr;
    float vmax = -INFINITY;
    #pragma unroll
    for (int bi = 0; bi < 4; ++bi)
      #pragma unroll
      for (int rg = 0; rg < 4; ++rg) {
        int n_g = v0 + wn * 64 + bi * 16 + lk * 4 + rg;
        if (n_g < VOCAB) vmax = fmaxf(vmax, acc[bi][bj][rg]);
      }
    vmax = fmaxf(vmax, __shfl_xor(vmax, 16, 64));
    vmax = fmaxf(vmax, __shfl_xor(vmax, 32, 64));
    float ssum = 0.f;
    const int t = tgt[m_g];
    #pragma unroll
    for (int bi = 0; bi < 4; ++bi)
      #pragma unroll
      for (int rg = 0; rg < 4; ++rg) {
        int n_g = v0 + wn * 64 + bi * 16 + lk * 4 + rg;
        float val = acc[bi][bj][rg];
        if (n_g < VOCAB) ssum += __expf(val - vmax);
        if (n_g == t) tlogit[m_g] = val;
      }
    ssum += __shfl_xor(ssum, 16, 64);
    ssum += __shfl_xor(ssum, 32, 64);
    if (lk == 0) stats[wn][wm * 64 + bj * 16 + lr] = make_float2(vmax, ssum);
  }
  __syncthreads();
  if (tid < BM) {
    float2 a = stats[0][tid], b = stats[1][tid];
    float M = fmaxf(a.x, b.x);
    float S = a.y * __expf(a.x - M) + b.y * __expf(b.x - M);
    partial[(size_t)(m0 + tid) * VCHUNKS + v] = make_float2(M, S);
  }
}

// ---------------------------------------------------------------------------
// Reduce: per-row merge of chunk partials -> lse; loss sum into d_out[0].
// ---------------------------------------------------------------------------
__device__ __forceinline__ void lse_merge(float& m, float& s, float M, float S) {
  if (S > 0.f) {
    if (M > m) { s = s * __expf(m - M) + S; m = M; }
    else       { s += S * __expf(M - m); }
  }
}

__global__ void lmhead_reduce(const float2* __restrict__ partial,
                              const float* __restrict__ tlogit,
                              const int* __restrict__ tgt,
                              float* __restrict__ out)
{
  const int wid = threadIdx.x >> 6;
  const int lane = threadIdx.x & 63;
  const int row = blockIdx.x * 4 + wid;
  float m = -INFINITY, s = 0.f;
  for (int c = lane; c < VCHUNKS; c += 64) {
    float2 p = partial[(size_t)row * VCHUNKS + c];
    lse_merge(m, s, p.x, p.y);
  }
  #pragma unroll
  for (int off = 1; off < 64; off <<= 1) {
    float M = __shfl_xor(m, off, 64);
    float S = __shfl_xor(s, off, 64);
    lse_merge(m, s, M, S);
  }
  if (lane == 0) {
    int t = tgt[row];
    if (t != IGNORE_INDEX) {
      float loss = m + __logf(s) - tlogit[row];
      atomicAdd(out, loss);
    }
  }
}

extern "C" void kernel_launch(void* const* d_in, const int* in_sizes, int n_in,
                              void* d_out, int out_size, void* d_ws, size_t ws_size,
                              hipStream_t stream) {
  const float* x = (const float*)d_in[0];
  const float* w = (const float*)d_in[1];
  const int* tgt = (const int*)d_in[2];
  float* out = (float*)d_out;

  const size_t w8_bytes = (size_t)VP * DDIM;             // ~103 MB
  const size_t x8_bytes = (size_t)N_TOK * DDIM;          // 8.4 MB
  const size_t part_bytes = (size_t)N_TOK * VCHUNKS * 8; // ~12.9 MB
  const size_t tl_bytes = (size_t)N_TOK * 4;
  const size_t need = w8_bytes + x8_bytes + part_bytes + tl_bytes;

  hipMemsetAsync(d_out, 0, sizeof(float), stream);

  if (ws_size >= need) {
    uint8_t* w8 = (uint8_t*)d_ws;
    uint8_t* xp = (uint8_t*)d_ws + w8_bytes;
    float2* partial = (float2*)((char*)d_ws + w8_bytes + x8_bytes);
    float* tlogit = (float*)((char*)d_ws + w8_bytes + x8_bytes + part_bytes);

    convert_x8<<<dim3(N_TOK * DDIM / 16 / 256), 256, 0, stream>>>(x, xp);
    transpose_w8<<<dim3(VP / 128, DDIM / 64), 256, 0, stream>>>(w, w8);
    lmhead_main<<<dim3(GRID_MAIN), 256, 0, stream>>>(w8, xp, tgt, partial, tlogit);
    lmhead_reduce<<<dim3(N_TOK / 4), 256, 0, stream>>>(partial, tlogit, tgt, out);
  } else {
    float2* partial = (float2*)d_ws;
    float* tlogit = (float*)((char*)d_ws + part_bytes);
    lmhead_partial_fb<<<dim3(GRID_MAIN), 256, 0, stream>>>(x, w, tgt, partial, tlogit);
    lmhead_reduce<<<dim3(N_TOK / 4), 256, 0, stream>>>(partial, tlogit, tgt, out);
  }
}

// Round 20
// 638.716 us; speedup vs baseline: 1.0859x; 1.0809x over previous
//
#include <hip/hip_runtime.h>
#include <hip/hip_bf16.h>
#include <stdint.h>

// Problem constants (from reference)
#define N_TOK 4096
#define DDIM  2048
#define VOCAB 50257
#define IGNORE_INDEX (-100)

// Tiling
#define BM 128
#define BN 128
#define BK 64                             // fp8 elements per K-tile (64 B/row)
#define NT (DDIM / BK)                    // 32 K-tiles
#define VCHUNKS ((VOCAB + BN - 1) / BN)   // 393
#define VP (VCHUNKS * BN)                 // 50304 padded vocab
#define ROW_TILES (N_TOK / BM)            // 32
#define GRID_MAIN (VCHUNKS * ROW_TILES)   // 12576

#define W_SCALE 32.0f                     // weight pre-scale (power of 2, exact)
#define W_INV   0.03125f
#define SCALE_1 0x7F7F7F7FU               // E8M0 127 = 2^0 in all 4 bytes

typedef float f32x4  __attribute__((ext_vector_type(4)));
typedef float f32x16 __attribute__((ext_vector_type(16)));
typedef int   i32x4  __attribute__((ext_vector_type(4)));
typedef int   i32x8  __attribute__((ext_vector_type(8)));

__device__ __forceinline__ uint32_t pack2bf(float a, float b) {
  uint32_t ua = __float_as_uint(a);
  uint32_t ub = __float_as_uint(b);
  uint32_t ra = (ua + 0x7fffu + ((ua >> 16) & 1u)) >> 16;
  uint32_t rb = (ub + 0x7fffu + ((ub >> 16) & 1u)) & 0xffff0000u;
  return (ra & 0xffffu) | rb;
}

// fp32 -> OCP e4m3 (RNE, saturate-to-448). Manual to guarantee RNE.
__device__ __forceinline__ uint32_t f32_to_e4m3(float f) {
  uint32_t u = __float_as_uint(f);
  uint32_t s = (u >> 24) & 0x80u;
  float a = fabsf(f);
  if (a >= 448.f) return s | 0x7Eu;           // saturate (max finite)
  if (a >= 0.015625f) {                        // normal range 2^-6 .. 448
    uint32_t m = __float_as_uint(a);
    m += 0x7FFFFu + ((m >> 20) & 1u);          // RNE at mantissa bit 20
    uint32_t e = (m >> 23) - 120u;             // exp-127+7 (carry handled)
    return s | (e << 3) | ((m >> 20) & 7u);
  }
  uint32_t m = (uint32_t)rintf(a * 512.f);     // subnormal: multiples of 2^-9
  return s | m;                                // m==8 encodes 2^-6 exactly
}

__device__ __forceinline__ void gload_lds16(const void* g, void* l) {
  __builtin_amdgcn_global_load_lds(
      (const __attribute__((address_space(1))) uint32_t*)g,
      (__attribute__((address_space(3))) uint32_t*)l, 16, 0, 0);
}

// ===========================================================================
// xp packed layout (B operand in MFMA order): for token-block tb (32 rows),
// K-tile T, piece p in {0,1}: 1KB chunk at ((tb*NT + T)*2 + p)*1024, where
// lane l = hi*32 + r5 holds row (tb*32+r5), k-bytes T*64 + hi*32 + p*16.
// loadB = coalesced 1KB global_load_dwordx4 per (bj, p).
// ===========================================================================

// ---------------------------------------------------------------------------
// Prep 1: x fp32[N][D] -> xp e4m3 packed (16 elems/thread)
// ---------------------------------------------------------------------------
__global__ __launch_bounds__(256) void convert_x8(const float* __restrict__ x,
                                                  uint8_t* __restrict__ xp) {
  int t = blockIdx.x * 256 + threadIdx.x;      // N*D/16 threads
  const int n = t >> 7;                        // row (D/16 = 128 pieces/row)
  const int q = t & 127;                       // 16B piece within row
  const float4* src = (const float4*)(x + (size_t)n * DDIM + q * 16);
  uint32_t u[4];
  #pragma unroll
  for (int g = 0; g < 4; ++g) {
    float4 f = src[g];
    u[g] = f32_to_e4m3(f.x) | (f32_to_e4m3(f.y) << 8) |
           (f32_to_e4m3(f.z) << 16) | (f32_to_e4m3(f.w) << 24);
  }
  const int T = q >> 2, rem = q & 3;
  const int hi = rem >> 1, p = rem & 1;
  const int tb = n >> 5, r5 = n & 31;
  const int l = hi * 32 + r5;
  uint8_t* dst = xp + (((size_t)tb * NT + T) * 2 + p) * 1024 + l * 16;
  *(uint4*)dst = make_uint4(u[0], u[1], u[2], u[3]);
}

// ---------------------------------------------------------------------------
// Prep 2 (r17-verified): w fp32[D][V] -> w8 e4m3[VP][D] linear k, x32.
// Tile = 64 k x 128 v; float4 loads -> LDS [64][68]; 32B/thread stores.
// ---------------------------------------------------------------------------
__global__ __launch_bounds__(256) void transpose_w8(const float* __restrict__ w,
                                                    uint8_t* __restrict__ w8) {
  __shared__ float t[64][68];
  const int vb = blockIdx.x * 128;  // VP/128 = 393 blocks
  const int kb = blockIdx.y * 64;   // D/64  = 32 blocks
  const int tid = threadIdx.x;

  const int fq = tid & 31;          // float4 column within tile (v = fq*4)
  const int r8 = tid >> 5;          // row 0..7 per pass
  if (vb + 128 <= VOCAB) {
    #pragma unroll
    for (int i = 0; i < 8; ++i) {
      int kl = r8 + i * 8;
      float4 f = *(const float4*)(w + (size_t)(kb + kl) * VOCAB + vb + fq * 4);
      *(float4*)&t[kl][fq * 4] = make_float4(f.x * W_SCALE, f.y * W_SCALE,
                                             f.z * W_SCALE, f.w * W_SCALE);
    }
  } else {
    #pragma unroll
    for (int i = 0; i < 8; ++i) {
      int kl = r8 + i * 8;
      #pragma unroll
      for (int c = 0; c < 4; ++c) {
        int v = vb + fq * 4 + c;
        t[kl][fq * 4 + c] =
            (v < VOCAB) ? w[(size_t)(kb + kl) * VOCAB + v] * W_SCALE : 0.f;
      }
    }
  }
  __syncthreads();

  // Phase 2: thread -> (v-row vl, 32B k-half). 256 threads = 128 v x 2.
  const int vl = tid >> 1, half = tid & 1;
  uint32_t u[8];
  #pragma unroll
  for (int g = 0; g < 8; ++g) {
    u[g] = 0;
    #pragma unroll
    for (int j = 0; j < 4; ++j)
      u[g] |= f32_to_e4m3(t[half * 32 + g * 4 + j][vl]) << (8 * j);
  }
  uint8_t* dst = w8 + (size_t)(vb + vl) * DDIM + kb + half * 32;
  *(uint4*)dst = make_uint4(u[0], u[1], u[2], u[3]);
  *(uint4*)(dst + 16) = make_uint4(u[4], u[5], u[6], u[7]);
}

// ---------------------------------------------------------------------------
// Main: MX-scaled FP8 GEMM (mfma_scale_f32_32x32x64_f8f6f4, scales = 1.0)
// fused with online-softmax partials. EXACT r14/r17 kernel (best measured:
// 483 us main, 640 us total): B from packed global (coalesced 1KB loads,
// double-buffered in regs), A via LDS (r10 placement, 2-buffer, distance-1
// prefetch), launch_bounds(256,3) -> no spill. Default (un-swizzled)
// chunk-major block order: concurrent same-panel blocks share L3 (r19
// showed any remap triples FETCH).
// A-operand LDS geometry (r8-verified): tile = 64 lines x 128 B; line j =
// rows {2j,2j+1}; logical 16B-unit lu = (row&1)*4 + k16 at phys lu ^ (j&7).
// C/D 32x32 layout (r8-verified): col(token) = lane&31,
// row(vocab) = (reg&3) + 8*(reg>>2) + 4*(lane>>5).
// ---------------------------------------------------------------------------
struct Bregs { i32x4 v[2][2]; };             // [bj][p] 16B pieces

__global__ __launch_bounds__(256, 3) void lmhead_main(
    const uint8_t* __restrict__ w8, const uint8_t* __restrict__ xp,
    const int* __restrict__ tgt,
    float2* __restrict__ partial, float* __restrict__ tlogit)
{
  __shared__ char lds[16384];          // 2 bufs x (A 8K)
  __shared__ float2 stats[2][BM];

  const int bid = blockIdx.x;
  const int v = bid >> 5;              // chunk-major: 32 row-tiles share panel
  const int r = bid & 31;
  const int v0 = v * BN;
  const int m0 = r * BM;
  const int tid = threadIdx.x;
  const int lane = tid & 63;
  const int wid = tid >> 6;
  const int wn = wid >> 1, wm = wid & 1;   // wn: vocab half, wm: token half

  f32x16 acc[2][2];
  #pragma unroll
  for (int i = 0; i < 2; ++i)
    #pragma unroll
    for (int j = 0; j < 2; ++j) acc[i][j] = (f32x16)0.f;

  // ---- A staging source mapping (per-lane constants; r10 placement) ----
  const int jj = lane >> 3;
  const int lu_s = (lane & 7) ^ jj;
  const int srow = 2 * jj + (lu_s >> 2);
  const int sk = (lu_s & 3) * 16;
  const uint8_t* wsrc = w8 + (size_t)(v0 + srow) * DDIM + sk;

  // ---- A fragment-read offsets (per-lane constants; r10 placement) ----
  const int r5 = lane & 31, hi = lane >> 5;
  const int j7 = (r5 >> 1) & 7;
  const int lu0 = ((r5 & 1) << 2) | (hi << 1);
  const int rdoff = (r5 >> 1) * 128 + ((lu0 ^ j7) << 4);
  const int aoff0 = wn * 4096 + rdoff;   // + bi*2048 per row-block

  // ---- B packed-global bases (per-lane constants) ----
  const int tb0 = (m0 >> 5) + wm * 2;    // token-32-block index for bj=0
  const uint8_t* xb0 = xp + ((size_t)tb0 * NT) * 2048 + lane * 16;
  const uint8_t* xb1 = xp + ((size_t)(tb0 + 1) * NT) * 2048 + lane * 16;

  // stage A of K-tile T into buf s: per wave 2 chunks (block: 8 x 1KB)
  auto stageA = [&](int T, int s) {
    char* Al = lds + s * 8192;
    const size_t ko = (size_t)T * BK;
    #pragma unroll
    for (int i = 0; i < 2; ++i) {
      int c = wid * 2 + i;                 // chunk 0..7 (16 rows each)
      gload_lds16(wsrc + (size_t)c * 16 * DDIM + ko, Al + c * 1024);
    }
  };
  // load B of K-tile T into register set (static indices only)
  auto loadB = [&](Bregs& B, int T) {
    const uint8_t* p0 = xb0 + (size_t)T * 2048;
    const uint8_t* p1 = xb1 + (size_t)T * 2048;
    B.v[0][0] = *(const i32x4*)(p0);
    B.v[0][1] = *(const i32x4*)(p0 + 1024);
    B.v[1][0] = *(const i32x4*)(p1);
    B.v[1][1] = *(const i32x4*)(p1 + 1024);
  };
  // compute one K-tile: A from LDS buf, B from registers
  auto computeT = [&](const char* Al, const Bregs& B) {
    i32x8 bv[2];
    #pragma unroll
    for (int bj = 0; bj < 2; ++bj)
      bv[bj] = __builtin_shufflevector(B.v[bj][0], B.v[bj][1],
                                       0, 1, 2, 3, 4, 5, 6, 7);
    #pragma unroll
    for (int bi = 0; bi < 2; ++bi) {
      i32x4 a0 = *(const i32x4*)(Al + (aoff0 + bi * 2048));
      i32x4 a1 = *(const i32x4*)(Al + ((aoff0 ^ 16) + bi * 2048));
      i32x8 av = __builtin_shufflevector(a0, a1, 0, 1, 2, 3, 4, 5, 6, 7);
      #pragma unroll
      for (int bj = 0; bj < 2; ++bj)
        acc[bi][bj] = __builtin_amdgcn_mfma_scale_f32_32x32x64_f8f6f4(
            av, bv[bj], acc[bi][bj], 0 /*A fmt fp8*/, 0 /*B fmt fp8*/,
            0, SCALE_1, 0, SCALE_1);
    }
  };

  Bregs B0, B1;
  stageA(0, 0);
  loadB(B0, 0);
  __syncthreads();                         // A buf0 ready

  for (int t = 0; t < NT; t += 2) {        // NT even; manual 2x unroll
    // half 1: compute tile t from buf0/B0; prefetch t+1 into buf1/B1
    if (t + 1 < NT) { stageA(t + 1, 1); loadB(B1, t + 1); }
    computeT(lds, B0);
    __syncthreads();                       // buf0 reads done; t+1 landed
    // half 2: compute tile t+1 from buf1/B1; prefetch t+2 into buf0/B0
    if (t + 2 < NT) { stageA(t + 2, 0); loadB(B0, t + 2); }
    computeT(lds + 8192, B1);
    __syncthreads();                       // buf1 reads done; t+2 landed
  }

  // ---- epilogue: per-token max & sum-exp over this wave's 64 vocab rows ----
  #pragma unroll
  for (int bj = 0; bj < 2; ++bj) {
    const int m_g = m0 + wm * 64 + bj * 32 + r5;
    float vmax = -INFINITY;
    #pragma unroll
    for (int bi = 0; bi < 2; ++bi) {
      #pragma unroll
      for (int rg = 0; rg < 16; ++rg) {
        int n_g = v0 + wn * 64 + bi * 32 + (rg & 3) + 8 * (rg >> 2) + 4 * hi;
        if (n_g < VOCAB) vmax = fmaxf(vmax, acc[bi][bj][rg] * W_INV);
      }
    }
    vmax = fmaxf(vmax, __shfl_xor(vmax, 32, 64));
    float ssum = 0.f;
    const int t = tgt[m_g];
    #pragma unroll
    for (int bi = 0; bi < 2; ++bi) {
      #pragma unroll
      for (int rg = 0; rg < 16; ++rg) {
        int n_g = v0 + wn * 64 + bi * 32 + (rg & 3) + 8 * (rg >> 2) + 4 * hi;
        float val = acc[bi][bj][rg] * W_INV;
        if (n_g < VOCAB) ssum += __expf(val - vmax);
        if (n_g == t) tlogit[m_g] = val;
      }
    }
    ssum += __shfl_xor(ssum, 32, 64);
    if (hi == 0) stats[wn][wm * 64 + bj * 32 + r5] = make_float2(vmax, ssum);
  }
  __syncthreads();
  if (tid < BM) {
    float2 a = stats[0][tid], b = stats[1][tid];
    float M = fmaxf(a.x, b.x);
    float S = a.y * __expf(a.x - M) + b.y * __expf(b.x - M);
    partial[(size_t)(m0 + tid) * VCHUNKS + v] = make_float2(M, S);
  }
}

// ---------------------------------------------------------------------------
// Fallback (round-1 kernel, bf16 path from fp32 inputs): if ws too small.
// ---------------------------------------------------------------------------
typedef short bf16x8 __attribute__((ext_vector_type(8)));

__global__ __launch_bounds__(256, 2) void lmhead_partial_fb(
    const float* __restrict__ x, const float* __restrict__ w,
    const int* __restrict__ tgt,
    float2* __restrict__ partial, float* __restrict__ tlogit)
{
  __shared__ uint4 xs[BM * 64 * 2 / 16];
  __shared__ uint4 wtl[BN * 64 * 2 / 16];
  __shared__ float2 stats[2][BM];

  const int bid = blockIdx.x;
  const int v = bid >> 5;
  const int r = bid & 31;
  const int v0 = v * BN;
  const int m0 = r * BM;
  const int tid = threadIdx.x;
  const int lane = tid & 63;
  const int wid = tid >> 6;
  const int wn = wid >> 1, wm = wid & 1;
  const int lr = lane & 15, lk = lane >> 4;

  f32x4 acc[4][4];
  #pragma unroll
  for (int i = 0; i < 4; ++i)
    #pragma unroll
    for (int j = 0; j < 4; ++j) acc[i][j] = (f32x4)0.f;

  char* xsb = (char*)xs;
  char* wtb = (char*)wtl;

  for (int kt = 0; kt < DDIM / 64; ++kt) {
    const int k0 = kt * 64;
    __syncthreads();
    #pragma unroll
    for (int i = 0; i < 4; ++i) {
      int t = tid + i * 256;
      int m = t >> 3, kg = t & 7;
      const float* gp = x + (size_t)(m0 + m) * DDIM + k0 + kg * 8;
      float4 f0 = *(const float4*)gp;
      float4 f1 = *(const float4*)(gp + 4);
      uint4 pk;
      pk.x = pack2bf(f0.x, f0.y); pk.y = pack2bf(f0.z, f0.w);
      pk.z = pack2bf(f1.x, f1.y); pk.w = pack2bf(f1.z, f1.w);
      int byte = (m * 128 + kg * 16) ^ ((m & 7) << 4);
      *(uint4*)(xsb + byte) = pk;
    }
    #pragma unroll
    for (int i = 0; i < 4; ++i) {
      int t = tid + i * 256;
      int n = t & 127, kg = t >> 7;
      int col = v0 + n;
      float f[8];
      if (col < VOCAB) {
        const float* gp = w + (size_t)(k0 + kg * 8) * VOCAB + col;
        #pragma unroll
        for (int kk = 0; kk < 8; ++kk) f[kk] = gp[(size_t)kk * VOCAB];
      } else {
        #pragma unroll
        for (int kk = 0; kk < 8; ++kk) f[kk] = 0.f;
      }
      uint4 pk;
      pk.x = pack2bf(f[0], f[1]); pk.y = pack2bf(f[2], f[3]);
      pk.z = pack2bf(f[4], f[5]); pk.w = pack2bf(f[6], f[7]);
      int byte = (n * 128 + kg * 16) ^ ((n & 7) << 4);
      *(uint4*)(wtb + byte) = pk;
    }
    __syncthreads();
    #pragma unroll
    for (int ks = 0; ks < 2; ++ks) {
      bf16x8 af[4], bfr[4];
      #pragma unroll
      for (int bi = 0; bi < 4; ++bi) {
        int row = wn * 64 + bi * 16 + lr;
        int byte = (row * 128 + ks * 64 + lk * 16) ^ ((row & 7) << 4);
        af[bi] = *(const bf16x8*)(wtb + byte);
      }
      #pragma unroll
      for (int bj = 0; bj < 4; ++bj) {
        int row = wm * 64 + bj * 16 + lr;
        int byte = (row * 128 + ks * 64 + lk * 16) ^ ((row & 7) << 4);
        bfr[bj] = *(const bf16x8*)(xsb + byte);
      }
      #pragma unroll
      for (int bi = 0; bi < 4; ++bi)
        #pragma unroll
        for (int bj = 0; bj < 4; ++bj)
          acc[bi][bj] = __builtin_amdgcn_mfma_f32_16x16x32_bf16(
              af[bi], bfr[bj], acc[bi][bj], 0, 0, 0);
    }
  }

  #pragma unroll
  for (int bj = 0; bj < 4; ++bj) {
    const int m_g = m0 + wm * 64 + bj * 16 + lr;
    float vmax = -INFINITY;
    #pragma unroll
    for (int bi = 0; bi < 4; ++bi)
      #pragma unroll
      for (int rg = 0; rg < 4; ++rg) {
        int n_g = v0 + wn * 64 + bi * 16 + lk * 4 + rg;
        if (n_g < VOCAB) vmax = fmaxf(vmax, acc[bi][bj][rg]);
      }
    vmax = fmaxf(vmax, __shfl_xor(vmax, 16, 64));
    vmax = fmaxf(vmax, __shfl_xor(vmax, 32, 64));
    float ssum = 0.f;
    const int t = tgt[m_g];
    #pragma unroll
    for (int bi = 0; bi < 4; ++bi)
      #pragma unroll
      for (int rg = 0; rg < 4; ++rg) {
        int n_g = v0 + wn * 64 + bi * 16 + lk * 4 + rg;
        float val = acc[bi][bj][rg];
        if (n_g < VOCAB) ssum += __expf(val - vmax);
        if (n_g == t) tlogit[m_g] = val;
      }
    ssum += __shfl_xor(ssum, 16, 64);
    ssum += __shfl_xor(ssum, 32, 64);
    if (lk == 0) stats[wn][wm * 64 + bj * 16 + lr] = make_float2(vmax, ssum);
  }
  __syncthreads();
  if (tid < BM) {
    float2 a = stats[0][tid], b = stats[1][tid];
    float M = fmaxf(a.x, b.x);
    float S = a.y * __expf(a.x - M) + b.y * __expf(b.x - M);
    partial[(size_t)(m0 + tid) * VCHUNKS + v] = make_float2(M, S);
  }
}

// ---------------------------------------------------------------------------
// Reduce: per-row merge of chunk partials -> lse; loss sum into d_out[0].
// ---------------------------------------------------------------------------
__device__ __forceinline__ void lse_merge(float& m, float& s, float M, float S) {
  if (S > 0.f) {
    if (M > m) { s = s * __expf(m - M) + S; m = M; }
    else       { s += S * __expf(M - m); }
  }
}

__global__ void lmhead_reduce(const float2* __restrict__ partial,
                              const float* __restrict__ tlogit,
                              const int* __restrict__ tgt,
                              float* __restrict__ out)
{
  const int wid = threadIdx.x >> 6;
  const int lane = threadIdx.x & 63;
  const int row = blockIdx.x * 4 + wid;
  float m = -INFINITY, s = 0.f;
  for (int c = lane; c < VCHUNKS; c += 64) {
    float2 p = partial[(size_t)row * VCHUNKS + c];
    lse_merge(m, s, p.x, p.y);
  }
  #pragma unroll
  for (int off = 1; off < 64; off <<= 1) {
    float M = __shfl_xor(m, off, 64);
    float S = __shfl_xor(s, off, 64);
    lse_merge(m, s, M, S);
  }
  if (lane == 0) {
    int t = tgt[row];
    if (t != IGNORE_INDEX) {
      float loss = m + __logf(s) - tlogit[row];
      atomicAdd(out, loss);
    }
  }
}

extern "C" void kernel_launch(void* const* d_in, const int* in_sizes, int n_in,
                              void* d_out, int out_size, void* d_ws, size_t ws_size,
                              hipStream_t stream) {
  const float* x = (const float*)d_in[0];
  const float* w = (const float*)d_in[1];
  const int* tgt = (const int*)d_in[2];
  float* out = (float*)d_out;

  const size_t w8_bytes = (size_t)VP * DDIM;             // ~103 MB
  const size_t x8_bytes = (size_t)N_TOK * DDIM;          // 8.4 MB
  const size_t part_bytes = (size_t)N_TOK * VCHUNKS * 8; // ~12.9 MB
  const size_t tl_bytes = (size_t)N_TOK * 4;
  const size_t need = w8_bytes + x8_bytes + part_bytes + tl_bytes;

  hipMemsetAsync(d_out, 0, sizeof(float), stream);

  if (ws_size >= need) {
    uint8_t* w8 = (uint8_t*)d_ws;
    uint8_t* xp = (uint8_t*)d_ws + w8_bytes;
    float2* partial = (float2*)((char*)d_ws + w8_bytes + x8_bytes);
    float* tlogit = (float*)((char*)d_ws + w8_bytes + x8_bytes + part_bytes);

    convert_x8<<<dim3(N_TOK * DDIM / 16 / 256), 256, 0, stream>>>(x, xp);
    transpose_w8<<<dim3(VP / 128, DDIM / 64), 256, 0, stream>>>(w, w8);
    lmhead_main<<<dim3(GRID_MAIN), 256, 0, stream>>>(w8, xp, tgt, partial, tlogit);
    lmhead_reduce<<<dim3(N_TOK / 4), 256, 0, stream>>>(partial, tlogit, tgt, out);
  } else {
    float2* partial = (float2*)d_ws;
    float* tlogit = (float*)((char*)d_ws + part_bytes);
    lmhead_partial_fb<<<dim3(GRID_MAIN), 256, 0, stream>>>(x, w, tgt, partial, tlogit);
    lmhead_reduce<<<dim3(N_TOK / 4), 256, 0, stream>>>(partial, tlogit, tgt, out);
  }
}